// Round 5
// baseline (98.900 us; speedup 1.0000x reference)
//
#include <hip/hip_runtime.h>

#define B_SZ 256
#define C_SZ 1152
#define MO   128            // M*O = 8*16
#define CSPL 32
#define CRNG (C_SZ / CSPL)  // 36 capsules per route block
#define CAPS_EPS 1e-8f

struct alignas(8) H4 { _Float16 h[4]; };
union PK2 { unsigned int u32; _Float16 h[2]; };

// ---------------------------------------------------------------------------
// K1: u_hat[c,b,mo] fp16. No LDS, no barriers.
// grid = 1152 blocks (one c each, XCD-chunked), block = 4 waves, wave =
// (c, b-quarter). Lane l holds W[c] rows mo=2l,2l+1 in 16 VGPRs; per b:
// 2 broadcast u loads + 16 FMA + packed-fp16 dword store (256B/wave).
__global__ __launch_bounds__(256) void caps_uhat(
    const float* __restrict__ u,      // [B,C,8]
    const float* __restrict__ W,      // [C,128,8]
    unsigned int* __restrict__ uhat)  // [C,B,64] dwords (= [C,B,128] fp16)
{
    const int bid = blockIdx.x;
    const int c   = (bid & 7) * 144 + (bid >> 3);  // 8 XCDs x 144 c chunks
    const int l   = threadIdx.x & 63;
    const int wv  = __builtin_amdgcn_readfirstlane(threadIdx.x >> 6);

    // W[c] floats l*16 .. l*16+15  ->  rows mo=2l (wa,wb) and mo=2l+1 (wc4,wd)
    const float4* wp =
        reinterpret_cast<const float4*>(W + (size_t)c * 1024) + l * 4;
    const float4 wa = wp[0], wb = wp[1], wc4 = wp[2], wd = wp[3];

    unsigned int* ub = uhat + (size_t)c * B_SZ * 64 + l;
    const int b0 = wv * 64;

    for (int bb = 0; bb < 64; bb += 8) {
#pragma unroll
        for (int k = 0; k < 8; ++k) {
            const int b = b0 + bb + k;
            const float4* up = reinterpret_cast<const float4*>(
                u + ((size_t)b * C_SZ + c) * 8);
            const float4 u0 = up[0], u1 = up[1];
            float h0 = wa.x*u0.x + wa.y*u0.y + wa.z*u0.z + wa.w*u0.w
                     + wb.x*u1.x + wb.y*u1.y + wb.z*u1.z + wb.w*u1.w;
            float h1 = wc4.x*u0.x + wc4.y*u0.y + wc4.z*u0.z + wc4.w*u0.w
                     + wd.x*u1.x + wd.y*u1.y + wd.z*u1.z + wd.w*u1.w;
            PK2 pk;
            pk.h[0] = (_Float16)h0;
            pk.h[1] = (_Float16)h1;
            ub[(size_t)b * 64] = pk.u32;   // fp16[mo=2l,2l+1] -> coalesced
        }
    }
}

// ---------------------------------------------------------------------------
// vcalc: vout = squash(sum_k part_in[k]) (+ addv if non-null).
// grid = B, block = 128.
__global__ __launch_bounds__(128) void caps_vcalc(
    const float* __restrict__ part_in,  // [CSPL,B,128]
    const float* __restrict__ addv,     // [B,128] or null
    float* __restrict__ vout)           // [B,128]
{
    const int b = blockIdx.x, t = threadIdx.x;
    float s = 0.f;
#pragma unroll
    for (int k = 0; k < CSPL; ++k)
        s += part_in[((size_t)k * B_SZ + b) * MO + t];
    float n2 = s * s;                   // 16-lane group = one m row
    n2 += __shfl_xor(n2, 1);
    n2 += __shfl_xor(n2, 2);
    n2 += __shfl_xor(n2, 4);
    n2 += __shfl_xor(n2, 8);
    float norm = sqrtf(n2);
    float v = (n2 / (1.f + n2)) * s / (norm + CAPS_EPS);
    if (addv) v += addv[(size_t)b * MO + t];
    vout[(size_t)b * MO + t] = v;
}

// ---------------------------------------------------------------------------
// route: one routing pass over materialized u_hat. UNIF=true is the R=0
// pass (uniform weights 1/8, no softmax, vbuf unused).
template <bool UNIF>
__global__ __launch_bounds__(256) void caps_route(
    const H4* __restrict__ uhat,        // [C,B,32]
    const float* __restrict__ vbuf,     // [B,128] (ignored if UNIF)
    float* __restrict__ part_out)       // [CSPL,B,128]
{
    const int bt  = blockIdx.x & 31;
    const int csp = blockIdx.x >> 5;
    const int tid = threadIdx.x;
    const int g   = tid >> 5;
    const int l   = tid & 31;
    const int b   = bt * 8 + g;
    const int mo4 = l * 4;

    float4 v4 = make_float4(0.f, 0.f, 0.f, 0.f);
    if (!UNIF)
        v4 = *reinterpret_cast<const float4*>(vbuf + (size_t)b * MO + mo4);
    float acc[4] = {0.f, 0.f, 0.f, 0.f};

    const int cbeg = csp * CRNG, cend = cbeg + CRNG;
    const H4* base = uhat + (size_t)b * 32 + l;  // stride B_SZ*32 per c

    H4 r0 = base[(size_t)cbeg * B_SZ * 32];
    H4 r1 = base[(size_t)(cbeg + 1) * B_SZ * 32];

    for (int c = cbeg; c < cend; c += 2) {
        H4 n0 = r0, n1 = r1;
        if (c + 2 < cend) {
            n0 = base[(size_t)(c + 2) * B_SZ * 32];
            n1 = base[(size_t)(c + 3) * B_SZ * 32];
        }
#pragma unroll
        for (int q = 0; q < 2; ++q) {
            H4 r = q ? r1 : r0;
            float uh0 = (float)r.h[0], uh1 = (float)r.h[1];
            float uh2 = (float)r.h[2], uh3 = (float)r.h[3];
            float cw;
            if (UNIF) {
                cw = 0.125f;
            } else {
                float uv = uh0 * v4.x + uh1 * v4.y + uh2 * v4.z + uh3 * v4.w;
                uv += __shfl_xor(uv, 1);      // reduce over o-quarters
                uv += __shfl_xor(uv, 2);      // -> uv[m] on 4 lanes
                float mx = fmaxf(uv, __shfl_xor(uv, 4));
                mx = fmaxf(mx, __shfl_xor(mx, 8));
                mx = fmaxf(mx, __shfl_xor(mx, 16));
                float e = expf(uv - mx);
                float den = e;
                den += __shfl_xor(den, 4);
                den += __shfl_xor(den, 8);
                den += __shfl_xor(den, 16);
                cw = e / den;
            }
            acc[0] = fmaf(cw, uh0, acc[0]);
            acc[1] = fmaf(cw, uh1, acc[1]);
            acc[2] = fmaf(cw, uh2, acc[2]);
            acc[3] = fmaf(cw, uh3, acc[3]);
        }
        r0 = n0; r1 = n1;
    }
    *reinterpret_cast<float4*>(part_out + ((size_t)csp * B_SZ + b) * MO + mo4) =
        make_float4(acc[0], acc[1], acc[2], acc[3]);
}

// ---------------------------------------------------------------------------
// Fallback (small-ws): round-1 fused kernel, needs only 384 KB of ws.
template <int R>
__global__ __launch_bounds__(256) void caps_small(
    const float* __restrict__ u, const float* __restrict__ W,
    const float* __restrict__ s_in, const float* __restrict__ v0_in,
    float* __restrict__ s_out, float* __restrict__ v0_out,
    float* __restrict__ out)
{
    const int b = blockIdx.x, tid = threadIdx.x;
    __shared__ float sh_v[8][17];
    __shared__ float sh_part[256][17];

    if (R >= 1) {
        if (tid < 128) {
            float val = s_in[b * 128 + tid];
            float n2 = val * val;
            n2 += __shfl_xor(n2, 1); n2 += __shfl_xor(n2, 2);
            n2 += __shfl_xor(n2, 4); n2 += __shfl_xor(n2, 8);
            float norm = sqrtf(n2);
            float v = (n2 / (1.f + n2)) * val / (norm + CAPS_EPS);
            int m = tid >> 4, o = tid & 15;
            if (R == 1) { v0_out[b * 128 + tid] = v; sh_v[m][o] = v; }
            else        { sh_v[m][o] = v + v0_in[b * 128 + tid]; }
        }
        __syncthreads();
    }
    const int c_local = tid >> 3, m = tid & 7;
    float s_acc[16];
#pragma unroll
    for (int o = 0; o < 16; ++o) s_acc[o] = 0.f;
    for (int cc = 0; cc < C_SZ; cc += 32) {
        const int c = cc + c_local;
        const float4* up = reinterpret_cast<const float4*>(
            u + (size_t)(b * C_SZ + c) * 8);
        float4 u0 = up[0], u1 = up[1];
        float u8[8] = {u0.x, u0.y, u0.z, u0.w, u1.x, u1.y, u1.z, u1.w};
        float uh[16];
        const float4* wp = reinterpret_cast<const float4*>(
            W + (size_t)((c * 8 + m) * 16) * 8);
#pragma unroll
        for (int o = 0; o < 16; ++o) {
            float4 w0 = wp[o * 2], w1 = wp[o * 2 + 1];
            uh[o] = w0.x * u8[0] + w0.y * u8[1] + w0.z * u8[2] + w0.w * u8[3] +
                    w1.x * u8[4] + w1.y * u8[5] + w1.z * u8[6] + w1.w * u8[7];
        }
        float cw;
        if (R == 0) cw = 0.125f;
        else {
            float uv = 0.f;
#pragma unroll
            for (int o = 0; o < 16; ++o) uv = fmaf(uh[o], sh_v[m][o], uv);
            float mx = uv;
            mx = fmaxf(mx, __shfl_xor(mx, 1));
            mx = fmaxf(mx, __shfl_xor(mx, 2));
            mx = fmaxf(mx, __shfl_xor(mx, 4));
            float e = expf(uv - mx);
            float den = e;
            den += __shfl_xor(den, 1); den += __shfl_xor(den, 2);
            den += __shfl_xor(den, 4);
            cw = e / den;
        }
#pragma unroll
        for (int o = 0; o < 16; ++o) s_acc[o] = fmaf(cw, uh[o], s_acc[o]);
    }
#pragma unroll
    for (int o = 0; o < 16; ++o) sh_part[tid][o] = s_acc[o];
    __syncthreads();
    if (tid < 128) {
        const int m2 = tid >> 4, o2 = tid & 15;
        float s = 0.f;
#pragma unroll
        for (int gg = 0; gg < 32; ++gg) s += sh_part[gg * 8 + m2][o2];
        if (R < 2) s_out[b * 128 + tid] = s;
        else {
            float n2 = s * s;
            n2 += __shfl_xor(n2, 1); n2 += __shfl_xor(n2, 2);
            n2 += __shfl_xor(n2, 4); n2 += __shfl_xor(n2, 8);
            float norm = sqrtf(n2);
            out[b * 128 + tid] = (n2 / (1.f + n2)) * s / (norm + CAPS_EPS);
        }
    }
}

extern "C" void kernel_launch(void* const* d_in, const int* in_sizes, int n_in,
                              void* d_out, int out_size, void* d_ws, size_t ws_size,
                              hipStream_t stream) {
    const float* u = (const float*)d_in[0];  // [256,1152,8]
    const float* W = (const float*)d_in[1];  // [1152,8,16,8]
    float* out = (float*)d_out;              // [256,8,16]

    const size_t UHAT_BYTES  = (size_t)C_SZ * B_SZ * MO * 2;     // 75.5 MB
    const size_t PART_FLOATS = (size_t)CSPL * B_SZ * MO;         // 4.19 MB
    const size_t NEED = UHAT_BYTES + 2 * PART_FLOATS * 4 + 2 * B_SZ * MO * 4;

    if (ws_size >= NEED) {
        unsigned int* uhat_w = (unsigned int*)d_ws;
        const H4* uhat_r = (const H4*)d_ws;
        float* partA = (float*)((char*)d_ws + UHAT_BYTES);
        float* partB = partA + PART_FLOATS;
        float* v0    = partB + PART_FLOATS;
        float* vsum  = v0 + B_SZ * MO;

        dim3 gridU(C_SZ), gridR(CSPL * 32), blk(256);
        caps_uhat<<<gridU, blk, 0, stream>>>(u, W, uhat_w);
        caps_route<true ><<<gridR, blk, 0, stream>>>(uhat_r, nullptr, partA);
        caps_vcalc<<<dim3(B_SZ), dim3(128), 0, stream>>>(partA, nullptr, v0);
        caps_route<false><<<gridR, blk, 0, stream>>>(uhat_r, v0, partB);
        caps_vcalc<<<dim3(B_SZ), dim3(128), 0, stream>>>(partB, v0, vsum);
        caps_route<false><<<gridR, blk, 0, stream>>>(uhat_r, vsum, partA);
        caps_vcalc<<<dim3(B_SZ), dim3(128), 0, stream>>>(partA, nullptr, out);
    } else {
        // small-ws fallback (round-1 path)
        float* sA = (float*)d_ws;
        float* sB = sA + 32768;
        float* v0 = sB + 32768;
        dim3 grid(B_SZ), blk(256);
        caps_small<0><<<grid, blk, 0, stream>>>(u, W, nullptr, nullptr, sA, nullptr, nullptr);
        caps_small<1><<<grid, blk, 0, stream>>>(u, W, sA, nullptr, sB, v0, nullptr);
        caps_small<2><<<grid, blk, 0, stream>>>(u, W, sB, v0, nullptr, nullptr, out);
    }
}

// Round 6
// 86.344 us; speedup vs baseline: 1.1454x; 1.1454x over previous
//
#include <hip/hip_runtime.h>

#define B_SZ 256
#define C_SZ 1152
#define MO   128            // M*O = 8*16
#define CSPL 32
#define CRNG (C_SZ / CSPL)  // 36 capsules per route block
#define CAPS_EPS 1e-8f

struct alignas(8) H4 { _Float16 h[4]; };
union PK2 { unsigned int u32; _Float16 h[2]; };

// ---------------------------------------------------------------------------
// K1: u_hat[c,b,mo] fp16. One c per block, 4 waves = 4 b-quarters.
// u[b][c][:] is staged into LDS ONCE per block (uncoalesced scatter, but a
// one-time ~256-line cost), so the hot loop has NO wave-uniform global loads
// (round-5 pathology: scalar-K$-missing s_load chains). W[c] rows mo=2l,2l+1
// live in 16 VGPRs per lane (coalesced float4 loads). Hot loop per b:
// 2 broadcast ds_read_b128 + 16 FMA + packed-fp16 coalesced dword store.
__global__ __launch_bounds__(256) void caps_uhat(
    const float* __restrict__ u,      // [B,C,8]
    const float* __restrict__ W,      // [C,128,8]
    unsigned int* __restrict__ uhat)  // [C,B,64] dwords (= [C,B,128] fp16)
{
    const int bid = blockIdx.x;
    const int c   = (bid & 7) * 144 + (bid >> 3);  // 8 XCDs x 144 c chunks
    const int tid = threadIdx.x;
    const int l   = tid & 63;
    const int wv  = tid >> 6;

    __shared__ __align__(16) float u_sh[B_SZ][8];   // 8 KB

    // W[c] floats l*16 .. l*16+15 -> rows mo=2l (wa,wb) and mo=2l+1 (wc4,wd)
    const float4* wp =
        reinterpret_cast<const float4*>(W + (size_t)c * 1024) + l * 4;
    const float4 wa = wp[0], wb = wp[1], wc4 = wp[2], wd = wp[3];

    // stage u[0:256][c][0:8] -> LDS (thread t owns b=t; once per block)
    {
        const float4* up = reinterpret_cast<const float4*>(
            u + ((size_t)tid * C_SZ + c) * 8);
        float4 a0 = up[0], a1 = up[1];
        *reinterpret_cast<float4*>(&u_sh[tid][0]) = a0;
        *reinterpret_cast<float4*>(&u_sh[tid][4]) = a1;
    }
    __syncthreads();

    unsigned int* ub = uhat + (size_t)c * B_SZ * 64 + l;
    const int b0 = wv * 64;

    for (int bb = 0; bb < 64; bb += 8) {
#pragma unroll
        for (int k = 0; k < 8; ++k) {
            const int b = b0 + bb + k;
            const float4 u0 = *reinterpret_cast<const float4*>(&u_sh[b][0]);
            const float4 u1 = *reinterpret_cast<const float4*>(&u_sh[b][4]);
            float h0 = wa.x*u0.x + wa.y*u0.y + wa.z*u0.z + wa.w*u0.w
                     + wb.x*u1.x + wb.y*u1.y + wb.z*u1.z + wb.w*u1.w;
            float h1 = wc4.x*u0.x + wc4.y*u0.y + wc4.z*u0.z + wc4.w*u0.w
                     + wd.x*u1.x + wd.y*u1.y + wd.z*u1.z + wd.w*u1.w;
            PK2 pk;
            pk.h[0] = (_Float16)h0;
            pk.h[1] = (_Float16)h1;
            ub[(size_t)b * 64] = pk.u32;   // fp16[mo=2l,2l+1] -> coalesced
        }
    }
}

// ---------------------------------------------------------------------------
// vcalc: vout = squash(sum_k part_in[k]) (+ addv if non-null).
// grid = B, block = 128.
__global__ __launch_bounds__(128) void caps_vcalc(
    const float* __restrict__ part_in,  // [CSPL,B,128]
    const float* __restrict__ addv,     // [B,128] or null
    float* __restrict__ vout)           // [B,128]
{
    const int b = blockIdx.x, t = threadIdx.x;
    float s = 0.f;
#pragma unroll
    for (int k = 0; k < CSPL; ++k)
        s += part_in[((size_t)k * B_SZ + b) * MO + t];
    float n2 = s * s;                   // 16-lane group = one m row
    n2 += __shfl_xor(n2, 1);
    n2 += __shfl_xor(n2, 2);
    n2 += __shfl_xor(n2, 4);
    n2 += __shfl_xor(n2, 8);
    float norm = sqrtf(n2);
    float v = (n2 / (1.f + n2)) * s / (norm + CAPS_EPS);
    if (addv) v += addv[(size_t)b * MO + t];
    vout[(size_t)b * MO + t] = v;
}

// ---------------------------------------------------------------------------
// route: one routing pass over materialized u_hat. UNIF=true is the R=0
// pass (uniform weights 1/8, no softmax, vbuf unused).
template <bool UNIF>
__global__ __launch_bounds__(256) void caps_route(
    const H4* __restrict__ uhat,        // [C,B,32]
    const float* __restrict__ vbuf,     // [B,128] (ignored if UNIF)
    float* __restrict__ part_out)       // [CSPL,B,128]
{
    const int bt  = blockIdx.x & 31;
    const int csp = blockIdx.x >> 5;
    const int tid = threadIdx.x;
    const int g   = tid >> 5;
    const int l   = tid & 31;
    const int b   = bt * 8 + g;
    const int mo4 = l * 4;

    float4 v4 = make_float4(0.f, 0.f, 0.f, 0.f);
    if (!UNIF)
        v4 = *reinterpret_cast<const float4*>(vbuf + (size_t)b * MO + mo4);
    float acc[4] = {0.f, 0.f, 0.f, 0.f};

    const int cbeg = csp * CRNG, cend = cbeg + CRNG;
    const H4* base = uhat + (size_t)b * 32 + l;  // stride B_SZ*32 per c

    H4 r0 = base[(size_t)cbeg * B_SZ * 32];
    H4 r1 = base[(size_t)(cbeg + 1) * B_SZ * 32];

    for (int c = cbeg; c < cend; c += 2) {
        H4 n0 = r0, n1 = r1;
        if (c + 2 < cend) {
            n0 = base[(size_t)(c + 2) * B_SZ * 32];
            n1 = base[(size_t)(c + 3) * B_SZ * 32];
        }
#pragma unroll
        for (int q = 0; q < 2; ++q) {
            H4 r = q ? r1 : r0;
            float uh0 = (float)r.h[0], uh1 = (float)r.h[1];
            float uh2 = (float)r.h[2], uh3 = (float)r.h[3];
            float cw;
            if (UNIF) {
                cw = 0.125f;
            } else {
                float uv = uh0 * v4.x + uh1 * v4.y + uh2 * v4.z + uh3 * v4.w;
                uv += __shfl_xor(uv, 1);      // reduce over o-quarters
                uv += __shfl_xor(uv, 2);      // -> uv[m] on 4 lanes
                float mx = fmaxf(uv, __shfl_xor(uv, 4));
                mx = fmaxf(mx, __shfl_xor(mx, 8));
                mx = fmaxf(mx, __shfl_xor(mx, 16));
                float e = expf(uv - mx);
                float den = e;
                den += __shfl_xor(den, 4);
                den += __shfl_xor(den, 8);
                den += __shfl_xor(den, 16);
                cw = e / den;
            }
            acc[0] = fmaf(cw, uh0, acc[0]);
            acc[1] = fmaf(cw, uh1, acc[1]);
            acc[2] = fmaf(cw, uh2, acc[2]);
            acc[3] = fmaf(cw, uh3, acc[3]);
        }
        r0 = n0; r1 = n1;
    }
    *reinterpret_cast<float4*>(part_out + ((size_t)csp * B_SZ + b) * MO + mo4) =
        make_float4(acc[0], acc[1], acc[2], acc[3]);
}

// ---------------------------------------------------------------------------
// Fallback (small-ws): round-1 fused kernel, needs only 384 KB of ws.
template <int R>
__global__ __launch_bounds__(256) void caps_small(
    const float* __restrict__ u, const float* __restrict__ W,
    const float* __restrict__ s_in, const float* __restrict__ v0_in,
    float* __restrict__ s_out, float* __restrict__ v0_out,
    float* __restrict__ out)
{
    const int b = blockIdx.x, tid = threadIdx.x;
    __shared__ float sh_v[8][17];
    __shared__ float sh_part[256][17];

    if (R >= 1) {
        if (tid < 128) {
            float val = s_in[b * 128 + tid];
            float n2 = val * val;
            n2 += __shfl_xor(n2, 1); n2 += __shfl_xor(n2, 2);
            n2 += __shfl_xor(n2, 4); n2 += __shfl_xor(n2, 8);
            float norm = sqrtf(n2);
            float v = (n2 / (1.f + n2)) * val / (norm + CAPS_EPS);
            int m = tid >> 4, o = tid & 15;
            if (R == 1) { v0_out[b * 128 + tid] = v; sh_v[m][o] = v; }
            else        { sh_v[m][o] = v + v0_in[b * 128 + tid]; }
        }
        __syncthreads();
    }
    const int c_local = tid >> 3, m = tid & 7;
    float s_acc[16];
#pragma unroll
    for (int o = 0; o < 16; ++o) s_acc[o] = 0.f;
    for (int cc = 0; cc < C_SZ; cc += 32) {
        const int c = cc + c_local;
        const float4* up = reinterpret_cast<const float4*>(
            u + (size_t)(b * C_SZ + c) * 8);
        float4 u0 = up[0], u1 = up[1];
        float u8[8] = {u0.x, u0.y, u0.z, u0.w, u1.x, u1.y, u1.z, u1.w};
        float uh[16];
        const float4* wp = reinterpret_cast<const float4*>(
            W + (size_t)((c * 8 + m) * 16) * 8);
#pragma unroll
        for (int o = 0; o < 16; ++o) {
            float4 w0 = wp[o * 2], w1 = wp[o * 2 + 1];
            uh[o] = w0.x * u8[0] + w0.y * u8[1] + w0.z * u8[2] + w0.w * u8[3] +
                    w1.x * u8[4] + w1.y * u8[5] + w1.z * u8[6] + w1.w * u8[7];
        }
        float cw;
        if (R == 0) cw = 0.125f;
        else {
            float uv = 0.f;
#pragma unroll
            for (int o = 0; o < 16; ++o) uv = fmaf(uh[o], sh_v[m][o], uv);
            float mx = uv;
            mx = fmaxf(mx, __shfl_xor(mx, 1));
            mx = fmaxf(mx, __shfl_xor(mx, 2));
            mx = fmaxf(mx, __shfl_xor(mx, 4));
            float e = expf(uv - mx);
            float den = e;
            den += __shfl_xor(den, 1); den += __shfl_xor(den, 2);
            den += __shfl_xor(den, 4);
            cw = e / den;
        }
#pragma unroll
        for (int o = 0; o < 16; ++o) s_acc[o] = fmaf(cw, uh[o], s_acc[o]);
    }
#pragma unroll
    for (int o = 0; o < 16; ++o) sh_part[tid][o] = s_acc[o];
    __syncthreads();
    if (tid < 128) {
        const int m2 = tid >> 4, o2 = tid & 15;
        float s = 0.f;
#pragma unroll
        for (int gg = 0; gg < 32; ++gg) s += sh_part[gg * 8 + m2][o2];
        if (R < 2) s_out[b * 128 + tid] = s;
        else {
            float n2 = s * s;
            n2 += __shfl_xor(n2, 1); n2 += __shfl_xor(n2, 2);
            n2 += __shfl_xor(n2, 4); n2 += __shfl_xor(n2, 8);
            float norm = sqrtf(n2);
            out[b * 128 + tid] = (n2 / (1.f + n2)) * s / (norm + CAPS_EPS);
        }
    }
}

extern "C" void kernel_launch(void* const* d_in, const int* in_sizes, int n_in,
                              void* d_out, int out_size, void* d_ws, size_t ws_size,
                              hipStream_t stream) {
    const float* u = (const float*)d_in[0];  // [256,1152,8]
    const float* W = (const float*)d_in[1];  // [1152,8,16,8]
    float* out = (float*)d_out;              // [256,8,16]

    const size_t UHAT_BYTES  = (size_t)C_SZ * B_SZ * MO * 2;     // 75.5 MB
    const size_t PART_FLOATS = (size_t)CSPL * B_SZ * MO;         // 4.19 MB
    const size_t NEED = UHAT_BYTES + 2 * PART_FLOATS * 4 + 2 * B_SZ * MO * 4;

    if (ws_size >= NEED) {
        unsigned int* uhat_w = (unsigned int*)d_ws;
        const H4* uhat_r = (const H4*)d_ws;
        float* partA = (float*)((char*)d_ws + UHAT_BYTES);
        float* partB = partA + PART_FLOATS;
        float* v0    = partB + PART_FLOATS;
        float* vsum  = v0 + B_SZ * MO;

        dim3 gridU(C_SZ), gridR(CSPL * 32), blk(256);
        caps_uhat<<<gridU, blk, 0, stream>>>(u, W, uhat_w);
        caps_route<true ><<<gridR, blk, 0, stream>>>(uhat_r, nullptr, partA);
        caps_vcalc<<<dim3(B_SZ), dim3(128), 0, stream>>>(partA, nullptr, v0);
        caps_route<false><<<gridR, blk, 0, stream>>>(uhat_r, v0, partB);
        caps_vcalc<<<dim3(B_SZ), dim3(128), 0, stream>>>(partB, v0, vsum);
        caps_route<false><<<gridR, blk, 0, stream>>>(uhat_r, vsum, partA);
        caps_vcalc<<<dim3(B_SZ), dim3(128), 0, stream>>>(partA, nullptr, out);
    } else {
        // small-ws fallback (round-1 path)
        float* sA = (float*)d_ws;
        float* sB = sA + 32768;
        float* v0 = sB + 32768;
        dim3 grid(B_SZ), blk(256);
        caps_small<0><<<grid, blk, 0, stream>>>(u, W, nullptr, nullptr, sA, nullptr, nullptr);
        caps_small<1><<<grid, blk, 0, stream>>>(u, W, sA, nullptr, sB, v0, nullptr);
        caps_small<2><<<grid, blk, 0, stream>>>(u, W, sB, v0, nullptr, nullptr, out);
    }
}